// Round 7
// baseline (401.576 us; speedup 1.0000x reference)
//
#include <hip/hip_runtime.h>
#include <cmath>

#define NODES 40000
#define EDGES 600000
#define HD    128
#define BN_EPS 1e-5f

typedef short bf16x8 __attribute__((ext_vector_type(8)));
typedef float f32x4  __attribute__((ext_vector_type(4)));
typedef unsigned short u16;
typedef unsigned int   u32;

__device__ __forceinline__ float bf2f(u16 u) {
  union { u32 i; float f; } v; v.i = ((u32)u) << 16; return v.f;
}
__device__ __forceinline__ u16 f2bf(float f) {
  union { float f; u32 i; } v; v.f = f;
  u32 r = v.i + 0x7FFF + ((v.i >> 16) & 1);   // RNE
  return (u16)(r >> 16);
}

struct WPrep { const float* s[8]; u16* d[8]; };

// ---------------- fused one-time prep ----------------
// blocks [0,5000): cast x to bf16 | [5000,5128): weight transpose+cast |
// [5128,5285): zero cursor
__global__ __launch_bounds__(256) void prep_all(const float4* __restrict__ x4,
                                                ushort4* __restrict__ xb4,
                                                WPrep p, int* __restrict__ cursor) {
  const int bid = blockIdx.x;
  const int tid = threadIdx.x;
  if (bid < 5000) {
    int i = bid * 256 + tid;
    float4 v = x4[i];
    ushort4 o;
    o.x = f2bf(v.x); o.y = f2bf(v.y); o.z = f2bf(v.z); o.w = f2bf(v.w);
    xb4[i] = o;
  } else if (bid < 5128) {
    int b = bid - 5000;
    int m = b >> 4, xx = b & 15;
    int N = (m == 7) ? 64 : 128;
    int tiles_n = N / 32;
    int tx = xx % tiles_n, tk = xx / tiles_n;
    if (tk >= 4) return;
    __shared__ float t[32][33];
    int c = tid & 31, r8 = tid >> 5;
    const float* s = p.s[m];
    for (int rr = 0; rr < 32; rr += 8)
      t[rr + r8][c] = s[(size_t)(tk * 32 + rr + r8) * N + tx * 32 + c];
    __syncthreads();
    u16* d = p.d[m];
    for (int rr = 0; rr < 32; rr += 8)
      d[(size_t)(tx * 32 + rr + r8) * HD + tk * 32 + c] = f2bf(t[c][rr + r8]);
  } else {
    int i = (bid - 5128) * 256 + tid;
    if (i < NODES) cursor[i] = 0;
  }
}

// ---------------- CSR build ----------------

__global__ __launch_bounds__(256) void hist_dst(const int* __restrict__ ei,
                                                int* __restrict__ deg) {
  int e = blockIdx.x * 256 + threadIdx.x;
  if (e < EDGES) atomicAdd(&deg[ei[EDGES + e]], 1);
}

// local exclusive scan per 1024-block; 40 blocks cover NODES
__global__ __launch_bounds__(1024) void scan1(const int* __restrict__ deg,
                                              int* __restrict__ off,
                                              int* __restrict__ bsum) {
  __shared__ int wsum[16];
  const int tid = threadIdx.x;
  const int lane = tid & 63, wv = tid >> 6;
  int i = blockIdx.x * 1024 + tid;
  int v = (i < NODES) ? deg[i] : 0;
  int s = v;
#pragma unroll
  for (int d = 1; d < 64; d <<= 1) {
    int t = __shfl_up(s, d, 64);
    if (lane >= d) s += t;
  }
  if (lane == 63) wsum[wv] = s;
  __syncthreads();
  if (wv == 0) {
    int ws = (lane < 16) ? wsum[lane] : 0;
#pragma unroll
    for (int d = 1; d < 16; d <<= 1) {
      int t = __shfl_up(ws, d, 64);
      if (lane >= d) ws += t;
    }
    if (lane < 16) wsum[lane] = ws;
  }
  __syncthreads();
  int base = (wv > 0 ? wsum[wv - 1] : 0);
  if (i < NODES) off[i] = base + s - v;
  if (tid == 1023) bsum[blockIdx.x] = base + s;
}

// each block re-scans the 40 block sums, adds prefix, mirrors into cursor
__global__ __launch_bounds__(1024) void scan23(int* __restrict__ off,
                                               int* __restrict__ cursor,
                                               const int* __restrict__ bsum) {
  __shared__ int pre_s;
  if (threadIdx.x < 64) {
    int lane = threadIdx.x;
    int v = (lane < 40) ? bsum[lane] : 0;
    int s = v;
#pragma unroll
    for (int d = 1; d < 64; d <<= 1) {
      int t = __shfl_up(s, d, 64);
      if (lane >= d) s += t;
    }
    if (lane == blockIdx.x) pre_s = s - v;
  }
  __syncthreads();
  int pre = pre_s;
  int i = blockIdx.x * 1024 + threadIdx.x;
  if (i < NODES) {
    int o = off[i] + pre;
    off[i] = o;
    cursor[i] = o;
  }
  if (blockIdx.x == 0 && threadIdx.x == 0) off[NODES] = EDGES;
}

__global__ __launch_bounds__(256) void fill_csr(const int* __restrict__ ei,
                                                int* __restrict__ cursor,
                                                int* __restrict__ slot) {
  int e = blockIdx.x * 256 + threadIdx.x;
  if (e >= EDGES) return;
  int s = ei[e];
  int d = ei[EDGES + e];
  int pos = atomicAdd(&cursor[d], 1);
  slot[pos] = s;
}

// ---------------- fused gather + GEMM1 (+BN+ELU) ----------------
// Per block: gather 64 rows of agg = x[i] + sum x[src] into LDS (bf16),
// then out[64 x 128] = BN_ELU(agg @ W1). Wt transposed [128][128].
// NOTE: out must NOT alias x (other blocks still read x rows).
__global__ __launch_bounds__(256) void gather_gemm(
    const u16* __restrict__ x, const int* __restrict__ off,
    const int* __restrict__ slot, const u16* __restrict__ Wt,
    const float* __restrict__ bias, const float* __restrict__ g,
    const float* __restrict__ bt, const float* __restrict__ mu,
    const float* __restrict__ var, u16* __restrict__ out) {
  constexpr int NC = 128, NT = NC / 16, PK = HD + 8;
  __shared__ u16 Wl[NC][PK];
  __shared__ u16 As[64][PK];

  const int tid = threadIdx.x;
  const int wv = tid >> 6, lane = tid & 63;

  for (int t = tid; t < NC * 16; t += 256) {
    int r = t >> 4, c8 = t & 15;
    *(bf16x8*)&Wl[r][c8 * 8] = *(const bf16x8*)(Wt + (size_t)r * HD + c8 * 8);
  }

  // gather: wave strip = 16 rows; half-wave (32 lanes x 8B) per node
  const int row0 = blockIdx.x * 64 + wv * 16;
  const int half = lane >> 5;
  const int hl = lane & 31;
#pragma unroll 1
  for (int it = 0; it < 8; ++it) {
    int r = it * 2 + half;
    int node = row0 + r;
    uint2 self = ((const uint2*)(x + (size_t)node * HD))[hl];
    float a0 = bf2f((u16)self.x), a1 = bf2f((u16)(self.x >> 16));
    float a2 = bf2f((u16)self.y), a3 = bf2f((u16)(self.y >> 16));
    int i0 = off[node], e1 = off[node + 1];
    for (int i = i0; i < e1; i += 8) {
      int ss[8];
      uint2 uu[8];
#pragma unroll
      for (int j = 0; j < 8; ++j) {
        int idx = i + j;
        ss[j] = slot[idx < e1 ? idx : i];
      }
#pragma unroll
      for (int j = 0; j < 8; ++j)
        uu[j] = ((const uint2*)(x + (size_t)ss[j] * HD))[hl];
#pragma unroll
      for (int j = 0; j < 8; ++j) {
        if (i + j < e1) {
          a0 += bf2f((u16)uu[j].x);
          a1 += bf2f((u16)(uu[j].x >> 16));
          a2 += bf2f((u16)uu[j].y);
          a3 += bf2f((u16)(uu[j].y >> 16));
        }
      }
    }
    u32 lo = (u32)f2bf(a0) | ((u32)f2bf(a1) << 16);
    u32 hi = (u32)f2bf(a2) | ((u32)f2bf(a3) << 16);
    uint2 pk; pk.x = lo; pk.y = hi;
    *(uint2*)&As[wv * 16 + r][hl * 4] = pk;
  }
  __syncthreads();

  const int col = lane & 15, kg = lane >> 4;
  f32x4 acc[NT];
#pragma unroll
  for (int t = 0; t < NT; ++t) acc[t] = (f32x4){0.f, 0.f, 0.f, 0.f};
#pragma unroll
  for (int kk = 0; kk < HD; kk += 32) {
    bf16x8 a = *(const bf16x8*)&As[wv * 16 + col][kk + kg * 8];
#pragma unroll
    for (int t = 0; t < NT; ++t) {
      bf16x8 b = *(const bf16x8*)&Wl[t * 16 + col][kk + kg * 8];
      acc[t] = __builtin_amdgcn_mfma_f32_16x16x32_bf16(a, b, acc[t], 0, 0, 0);
    }
  }

#pragma unroll
  for (int t = 0; t < NT; ++t) {
    int c = t * 16 + col;
    float rs = rsqrtf(var[c] + BN_EPS) * g[c];
    float bb = bt[c] + (bias[c] - mu[c]) * rs;
#pragma unroll
    for (int r = 0; r < 4; ++r) {
      float v = acc[t][r] * rs + bb;
      v = v > 0.f ? v : expm1f(v);
      As[wv * 16 + kg * 4 + r][c] = f2bf(v);
    }
  }
  __syncthreads();

  {
    int r0 = lane >> 4, seg = lane & 15;
#pragma unroll
    for (int rr = 0; rr < 16; rr += 4) {
      int row = rr + r0;
      *(float4*)((char*)(out + (size_t)(row0 + row) * NC) + seg * 16) =
          *(const float4*)((const char*)&As[wv * 16 + row][0] + seg * 16);
    }
  }
}

// ---------------- standalone MFMA GEMM (+epilogue) ----------------
// EPI: 2=ELU, 3=none. A bf16 row-major from global, Wt transposed [NC][128].
template <int NC, int EPI, typename OT>
__global__ __launch_bounds__(256) void gemm_mfma(
    const u16* __restrict__ A, const u16* __restrict__ Wt,
    const float* __restrict__ bias, OT* __restrict__ out) {
  constexpr int NT = NC / 16;
  constexpr int PK = HD + 8;
  __shared__ u16 Wl[NC][PK];
  __shared__ OT stage[4][16][NC];
  static_assert(NC * sizeof(OT) == 256, "store path assumes 256B rows");

  const int tid = threadIdx.x;
  const int wv = tid >> 6, lane = tid & 63;
  const int col = lane & 15, kg = lane >> 4;

  for (int t = tid; t < NC * 16; t += 256) {
    int r = t >> 4, c8 = t & 15;
    *(bf16x8*)&Wl[r][c8 * 8] = *(const bf16x8*)(Wt + (size_t)r * HD + c8 * 8);
  }
  __syncthreads();

  const int strip = blockIdx.x * 4 + wv;
  const u16* Arow = A + (size_t)(strip * 16 + col) * HD;

  f32x4 acc[NT];
#pragma unroll
  for (int t = 0; t < NT; ++t) acc[t] = (f32x4){0.f, 0.f, 0.f, 0.f};
#pragma unroll
  for (int kk = 0; kk < HD; kk += 32) {
    bf16x8 a = *(const bf16x8*)(Arow + kk + kg * 8);
#pragma unroll
    for (int t = 0; t < NT; ++t) {
      bf16x8 b = *(const bf16x8*)&Wl[t * 16 + col][kk + kg * 8];
      acc[t] = __builtin_amdgcn_mfma_f32_16x16x32_bf16(a, b, acc[t], 0, 0, 0);
    }
  }

#pragma unroll
  for (int t = 0; t < NT; ++t) {
    int c = t * 16 + col;
    float bb = bias[c];
#pragma unroll
    for (int r = 0; r < 4; ++r) {
      float v = acc[t][r] + bb;
      if (EPI == 2) v = v > 0.f ? v : expm1f(v);
      if constexpr (sizeof(OT) == 2) stage[wv][kg * 4 + r][c] = (OT)f2bf(v);
      else                           stage[wv][kg * 4 + r][c] = v;
    }
  }
  __syncthreads();

  {
    int r0 = lane >> 4, seg = lane & 15;
#pragma unroll
    for (int rr = 0; rr < 16; rr += 4) {
      int row = rr + r0;
      *(float4*)((char*)(out + (size_t)(strip * 16 + row) * NC) + seg * 16) =
          *(const float4*)((const char*)&stage[wv][row][0] + seg * 16);
    }
  }
}

// ---------------- fused head: ELU(A@W1+b1) @ W2 + b2 -> fp32 ----------------
__global__ __launch_bounds__(256) void head_fused(
    const u16* __restrict__ A, const u16* __restrict__ W1t,
    const float* __restrict__ b1, const u16* __restrict__ W2t,
    const float* __restrict__ b2, float* __restrict__ out) {
  constexpr int PK = HD + 8;
  __shared__ u16 W1[128][PK];
  __shared__ u16 W2[64][PK];
  __shared__ u16 H[64][PK];

  const int tid = threadIdx.x;
  const int wv = tid >> 6, lane = tid & 63;
  const int col = lane & 15, kg = lane >> 4;

  for (int t = tid; t < 128 * 16; t += 256) {
    int r = t >> 4, c8 = t & 15;
    *(bf16x8*)&W1[r][c8 * 8] = *(const bf16x8*)(W1t + (size_t)r * HD + c8 * 8);
  }
  for (int t = tid; t < 64 * 16; t += 256) {
    int r = t >> 4, c8 = t & 15;
    *(bf16x8*)&W2[r][c8 * 8] = *(const bf16x8*)(W2t + (size_t)r * HD + c8 * 8);
  }
  __syncthreads();

  const int strip = blockIdx.x * 4 + wv;
  const u16* Arow = A + (size_t)(strip * 16 + col) * HD;

  // lin1
  f32x4 acc[8];
#pragma unroll
  for (int t = 0; t < 8; ++t) acc[t] = (f32x4){0.f, 0.f, 0.f, 0.f};
#pragma unroll
  for (int kk = 0; kk < HD; kk += 32) {
    bf16x8 a = *(const bf16x8*)(Arow + kk + kg * 8);
#pragma unroll
    for (int t = 0; t < 8; ++t) {
      bf16x8 b = *(const bf16x8*)&W1[t * 16 + col][kk + kg * 8];
      acc[t] = __builtin_amdgcn_mfma_f32_16x16x32_bf16(a, b, acc[t], 0, 0, 0);
    }
  }
#pragma unroll
  for (int t = 0; t < 8; ++t) {
    int c = t * 16 + col;
    float bb = b1[c];
#pragma unroll
    for (int r = 0; r < 4; ++r) {
      float v = acc[t][r] + bb;
      v = v > 0.f ? v : expm1f(v);
      H[wv * 16 + kg * 4 + r][c] = f2bf(v);
    }
  }
  __syncthreads();

  // lin2 (A = H own strip rows)
  f32x4 acc2[4];
#pragma unroll
  for (int t = 0; t < 4; ++t) acc2[t] = (f32x4){0.f, 0.f, 0.f, 0.f};
#pragma unroll
  for (int kk = 0; kk < HD; kk += 32) {
    bf16x8 a = *(const bf16x8*)&H[wv * 16 + col][kk + kg * 8];
#pragma unroll
    for (int t = 0; t < 4; ++t) {
      bf16x8 b = *(const bf16x8*)&W2[t * 16 + col][kk + kg * 8];
      acc2[t] = __builtin_amdgcn_mfma_f32_16x16x32_bf16(a, b, acc2[t], 0, 0, 0);
    }
  }
  __syncthreads();
#pragma unroll
  for (int t = 0; t < 4; ++t) {
    int c = t * 16 + col;
    float bb = b2[c];
#pragma unroll
    for (int r = 0; r < 4; ++r) {
      float* Hr = (float*)&H[wv * 16 + kg * 4 + r][0];
      Hr[c] = acc2[t][r] + bb;
    }
  }
  __syncthreads();
  {
    int r0 = lane >> 4, seg = lane & 15;
#pragma unroll
    for (int rr = 0; rr < 16; rr += 4) {
      int row = rr + r0;
      *(float4*)((char*)(out + (size_t)(strip * 16 + row) * 64) + seg * 16) =
          *(const float4*)((const char*)&H[wv * 16 + row][0] + seg * 16);
    }
  }
}

extern "C" void kernel_launch(void* const* d_in, const int* in_sizes, int n_in,
                              void* d_out, int out_size, void* d_ws, size_t ws_size,
                              hipStream_t stream) {
  const float* x = (const float*)d_in[0];
  const int* ei  = (const int*)d_in[1];
  const float* p[30];
  for (int i = 0; i < 30 && i < n_in; ++i) p[i] = (const float*)d_in[i];

  const size_t FEAT = (size_t)NODES * HD;
  u16* xb   = (u16*)d_ws;     // doubles as the persistent 'cur' buffer
  u16* tmp  = xb + FEAT;      // gather_gemm target
  u16* wt   = tmp + FEAT;
  u16* wts[8];
  for (int m = 0; m < 8; ++m) wts[m] = wt + (size_t)m * HD * HD;
  int* off    = (int*)(wt + 8 * HD * HD);
  int* cursor = off + (NODES + 1);
  int* slot   = cursor + NODES;
  int* bsum   = slot + EDGES;

  dim3 blk(256);
  const int edgeGrid = (EDGES + 255) / 256;   // 2344
  const int fuseGrid = NODES / 64;            // 625
  const int scanGrid = 40;

  // prep (cast x, weight transpose+cast, zero cursor)
  WPrep wp;
  const int widx[8] = {2, 8, 10, 16, 18, 24, 26, 28};
  for (int m = 0; m < 8; ++m) { wp.s[m] = p[widx[m]]; wp.d[m] = wts[m]; }
  prep_all<<<5285, blk, 0, stream>>>((const float4*)x, (ushort4*)xb, wp, cursor);

  // CSR (by dst), reused by all 3 layers
  hist_dst<<<edgeGrid, blk, 0, stream>>>(ei, cursor);
  scan1<<<scanGrid, 1024, 0, stream>>>(cursor, off, bsum);
  scan23<<<scanGrid, 1024, 0, stream>>>(off, cursor, bsum);
  fill_csr<<<edgeGrid, blk, 0, stream>>>(ei, cursor, slot);

  // 3 GIN layers. Liveness: cur dead after gather_gemm -> gemm2 writes cur.
  // cur/tmp are ALWAYS distinct (fixes R6's in-place race).
  for (int l = 0; l < 3; ++l) {
    const int base = 2 + l * 8;
    gather_gemm<<<fuseGrid, blk, 0, stream>>>(
        xb, off, slot, wts[l * 2], p[base + 1], p[base + 2], p[base + 3],
        p[base + 4], p[base + 5], tmp);
    gemm_mfma<128, 2, u16><<<fuseGrid, blk, 0, stream>>>(
        tmp, wts[l * 2 + 1], p[base + 7], xb);
  }

  // fused head -> fp32 out
  head_fused<<<fuseGrid, blk, 0, stream>>>(
      xb, wts[6], p[27], wts[7], p[29], (float*)d_out);
}

// Round 8
// 377.421 us; speedup vs baseline: 1.0640x; 1.0640x over previous
//
#include <hip/hip_runtime.h>
#include <cmath>

#define NODES 40000
#define EDGES 600000
#define HD    128
#define BN_EPS 1e-5f

typedef short bf16x8 __attribute__((ext_vector_type(8)));
typedef float f32x4  __attribute__((ext_vector_type(4)));
typedef unsigned short u16;
typedef unsigned int   u32;

__device__ __forceinline__ float bf2f(u16 u) {
  union { u32 i; float f; } v; v.i = ((u32)u) << 16; return v.f;
}
__device__ __forceinline__ u16 f2bf(float f) {
  union { float f; u32 i; } v; v.f = f;
  u32 r = v.i + 0x7FFF + ((v.i >> 16) & 1);   // RNE
  return (u16)(r >> 16);
}

struct WPrep { const float* s[8]; u16* d[8]; };

// ---------------- fused one-time prep ----------------
__global__ __launch_bounds__(256) void prep_all(const float4* __restrict__ x4,
                                                ushort4* __restrict__ xb4,
                                                WPrep p, int* __restrict__ cursor) {
  const int bid = blockIdx.x;
  const int tid = threadIdx.x;
  if (bid < 5000) {
    int i = bid * 256 + tid;
    float4 v = x4[i];
    ushort4 o;
    o.x = f2bf(v.x); o.y = f2bf(v.y); o.z = f2bf(v.z); o.w = f2bf(v.w);
    xb4[i] = o;
  } else if (bid < 5128) {
    int b = bid - 5000;
    int m = b >> 4, xx = b & 15;
    int N = (m == 7) ? 64 : 128;
    int tiles_n = N / 32;
    int tx = xx % tiles_n, tk = xx / tiles_n;
    if (tk >= 4) return;
    __shared__ float t[32][33];
    int c = tid & 31, r8 = tid >> 5;
    const float* s = p.s[m];
    for (int rr = 0; rr < 32; rr += 8)
      t[rr + r8][c] = s[(size_t)(tk * 32 + rr + r8) * N + tx * 32 + c];
    __syncthreads();
    u16* d = p.d[m];
    for (int rr = 0; rr < 32; rr += 8)
      d[(size_t)(tx * 32 + rr + r8) * HD + tk * 32 + c] = f2bf(t[c][rr + r8]);
  } else {
    int i = (bid - 5128) * 256 + tid;
    if (i < NODES) cursor[i] = 0;
  }
}

// ---------------- CSR build ----------------

__global__ __launch_bounds__(256) void hist_dst(const int* __restrict__ ei,
                                                int* __restrict__ deg) {
  int e = blockIdx.x * 256 + threadIdx.x;
  if (e < EDGES) atomicAdd(&deg[ei[EDGES + e]], 1);
}

__global__ __launch_bounds__(1024) void scan1(const int* __restrict__ deg,
                                              int* __restrict__ off,
                                              int* __restrict__ bsum) {
  __shared__ int wsum[16];
  const int tid = threadIdx.x;
  const int lane = tid & 63, wv = tid >> 6;
  int i = blockIdx.x * 1024 + tid;
  int v = (i < NODES) ? deg[i] : 0;
  int s = v;
#pragma unroll
  for (int d = 1; d < 64; d <<= 1) {
    int t = __shfl_up(s, d, 64);
    if (lane >= d) s += t;
  }
  if (lane == 63) wsum[wv] = s;
  __syncthreads();
  if (wv == 0) {
    int ws = (lane < 16) ? wsum[lane] : 0;
#pragma unroll
    for (int d = 1; d < 16; d <<= 1) {
      int t = __shfl_up(ws, d, 64);
      if (lane >= d) ws += t;
    }
    if (lane < 16) wsum[lane] = ws;
  }
  __syncthreads();
  int base = (wv > 0 ? wsum[wv - 1] : 0);
  if (i < NODES) off[i] = base + s - v;
  if (tid == 1023) bsum[blockIdx.x] = base + s;
}

__global__ __launch_bounds__(1024) void scan23(int* __restrict__ off,
                                               int* __restrict__ cursor,
                                               const int* __restrict__ bsum) {
  __shared__ int pre_s;
  if (threadIdx.x < 64) {
    int lane = threadIdx.x;
    int v = (lane < 40) ? bsum[lane] : 0;
    int s = v;
#pragma unroll
    for (int d = 1; d < 64; d <<= 1) {
      int t = __shfl_up(s, d, 64);
      if (lane >= d) s += t;
    }
    if (lane == blockIdx.x) pre_s = s - v;
  }
  __syncthreads();
  int pre = pre_s;
  int i = blockIdx.x * 1024 + threadIdx.x;
  if (i < NODES) {
    int o = off[i] + pre;
    off[i] = o;
    cursor[i] = o;
  }
  if (blockIdx.x == 0 && threadIdx.x == 0) off[NODES] = EDGES;
}

__global__ __launch_bounds__(256) void fill_csr(const int* __restrict__ ei,
                                                int* __restrict__ cursor,
                                                int* __restrict__ slot) {
  int e = blockIdx.x * 256 + threadIdx.x;
  if (e >= EDGES) return;
  int s = ei[e];
  int d = ei[EDGES + e];
  int pos = atomicAdd(&cursor[d], 1);
  slot[pos] = s;
}

// -------- standalone gather (zero LDS, max occupancy) --------
// agg[i] = x[i] + sum_{e: dst==i} x[src[e]]; half-wave (32 lanes x uint2) per
// node -> 16 row-loads in flight per wave. Grid: NODES/8 blocks.
__global__ __launch_bounds__(256) void gather_agg(const u16* __restrict__ x,
                                                  const int* __restrict__ off,
                                                  const int* __restrict__ slot,
                                                  u16* __restrict__ agg) {
  const int tid = threadIdx.x;
  const int half = (tid >> 5) & 1;
  const int hl = tid & 31;
  const int node = blockIdx.x * 8 + (tid >> 6) * 2 + half;

  uint2 self = ((const uint2*)(x + (size_t)node * HD))[hl];
  float a0 = bf2f((u16)self.x), a1 = bf2f((u16)(self.x >> 16));
  float a2 = bf2f((u16)self.y), a3 = bf2f((u16)(self.y >> 16));
  int i0 = off[node], e1 = off[node + 1];
  for (int i = i0; i < e1; i += 8) {
    int ss[8];
    uint2 uu[8];
#pragma unroll
    for (int j = 0; j < 8; ++j) {
      int idx = i + j;
      ss[j] = slot[idx < e1 ? idx : i];
    }
#pragma unroll
    for (int j = 0; j < 8; ++j)
      uu[j] = ((const uint2*)(x + (size_t)ss[j] * HD))[hl];
#pragma unroll
    for (int j = 0; j < 8; ++j) {
      if (i + j < e1) {
        a0 += bf2f((u16)uu[j].x);
        a1 += bf2f((u16)(uu[j].x >> 16));
        a2 += bf2f((u16)uu[j].y);
        a3 += bf2f((u16)(uu[j].y >> 16));
      }
    }
  }
  uint2 pk;
  pk.x = (u32)f2bf(a0) | ((u32)f2bf(a1) << 16);
  pk.y = (u32)f2bf(a2) | ((u32)f2bf(a3) << 16);
  ((uint2*)(agg + (size_t)node * HD))[hl] = pk;
}

// ---------------- fused MLP: ELU(BN(A@W1+b1)) @ W2 + b2, ELU -> bf16 ------
// A: agg bf16 [NODES][128]. W1t/W2t transposed [128][128]. H overlays W1's
// LDS after GEMM1 (one barrier; each wave reads only its OWN H strip).
__global__ __launch_bounds__(256) void mlp_fused(
    const u16* __restrict__ A, const u16* __restrict__ W1t,
    const float* __restrict__ b1, const float* __restrict__ g,
    const float* __restrict__ bt, const float* __restrict__ mu,
    const float* __restrict__ var, const u16* __restrict__ W2t,
    const float* __restrict__ b2, u16* __restrict__ out) {
  constexpr int PK = HD + 8;
  __shared__ u16 W1H[128][PK];   // W1, then H (first 64 rows) after barrier
  __shared__ u16 W2[128][PK];

  const int tid = threadIdx.x;
  const int wv = tid >> 6, lane = tid & 63;
  const int col = lane & 15, kg = lane >> 4;

  for (int t = tid; t < 128 * 16; t += 256) {
    int r = t >> 4, c8 = t & 15;
    *(bf16x8*)&W1H[r][c8 * 8] = *(const bf16x8*)(W1t + (size_t)r * HD + c8 * 8);
    *(bf16x8*)&W2[r][c8 * 8]  = *(const bf16x8*)(W2t + (size_t)r * HD + c8 * 8);
  }
  __syncthreads();

  const int strip = blockIdx.x * 4 + wv;
  const u16* Arow = A + (size_t)(strip * 16 + col) * HD;

  // GEMM1: A from global, B from W1H
  f32x4 acc[8];
#pragma unroll
  for (int t = 0; t < 8; ++t) acc[t] = (f32x4){0.f, 0.f, 0.f, 0.f};
#pragma unroll
  for (int kk = 0; kk < HD; kk += 32) {
    bf16x8 a = *(const bf16x8*)(Arow + kk + kg * 8);
#pragma unroll
    for (int t = 0; t < 8; ++t) {
      bf16x8 b = *(const bf16x8*)&W1H[t * 16 + col][kk + kg * 8];
      acc[t] = __builtin_amdgcn_mfma_f32_16x16x32_bf16(a, b, acc[t], 0, 0, 0);
    }
  }
  __syncthreads();  // all waves done reading W1 before H overlays it

  // BN + ELU -> H rows (own strip)
#pragma unroll
  for (int t = 0; t < 8; ++t) {
    int c = t * 16 + col;
    float rs = rsqrtf(var[c] + BN_EPS) * g[c];
    float bb = bt[c] + (b1[c] - mu[c]) * rs;
#pragma unroll
    for (int r = 0; r < 4; ++r) {
      float v = acc[t][r] * rs + bb;
      v = v > 0.f ? v : expm1f(v);
      W1H[wv * 16 + kg * 4 + r][c] = f2bf(v);
    }
  }
  // no barrier: GEMM2 A-frags come from this wave's own strip only

  // GEMM2: A from H (own strip), B from W2
  f32x4 acc2[8];
#pragma unroll
  for (int t = 0; t < 8; ++t) acc2[t] = (f32x4){0.f, 0.f, 0.f, 0.f};
#pragma unroll
  for (int kk = 0; kk < HD; kk += 32) {
    bf16x8 a = *(const bf16x8*)&W1H[wv * 16 + col][kk + kg * 8];
#pragma unroll
    for (int t = 0; t < 8; ++t) {
      bf16x8 b = *(const bf16x8*)&W2[t * 16 + col][kk + kg * 8];
      acc2[t] = __builtin_amdgcn_mfma_f32_16x16x32_bf16(a, b, acc2[t], 0, 0, 0);
    }
  }

  // ELU -> stage into own strip rows (overwrite own H, no cross-wave readers)
#pragma unroll
  for (int t = 0; t < 8; ++t) {
    int c = t * 16 + col;
    float bb = b2[c];
#pragma unroll
    for (int r = 0; r < 4; ++r) {
      float v = acc2[t][r] + bb;
      v = v > 0.f ? v : expm1f(v);
      W1H[wv * 16 + kg * 4 + r][c] = f2bf(v);
    }
  }

  // coalesced 16B store-back of own strip
  {
    int r0 = lane >> 4, seg = lane & 15;
#pragma unroll
    for (int rr = 0; rr < 16; rr += 4) {
      int row = rr + r0;
      *(float4*)((char*)(out + (size_t)(strip * 16 + row) * HD) + seg * 16) =
          *(const float4*)((const char*)&W1H[wv * 16 + row][0] + seg * 16);
    }
  }
}

// ---------------- fused head: ELU(A@W1+b1) @ W2 + b2 -> fp32 ----------------
__global__ __launch_bounds__(256) void head_fused(
    const u16* __restrict__ A, const u16* __restrict__ W1t,
    const float* __restrict__ b1, const u16* __restrict__ W2t,
    const float* __restrict__ b2, float* __restrict__ out) {
  constexpr int PK = HD + 8;
  __shared__ u16 W1[128][PK];
  __shared__ u16 W2[64][PK];
  __shared__ u16 H[64][PK];

  const int tid = threadIdx.x;
  const int wv = tid >> 6, lane = tid & 63;
  const int col = lane & 15, kg = lane >> 4;

  for (int t = tid; t < 128 * 16; t += 256) {
    int r = t >> 4, c8 = t & 15;
    *(bf16x8*)&W1[r][c8 * 8] = *(const bf16x8*)(W1t + (size_t)r * HD + c8 * 8);
  }
  for (int t = tid; t < 64 * 16; t += 256) {
    int r = t >> 4, c8 = t & 15;
    *(bf16x8*)&W2[r][c8 * 8] = *(const bf16x8*)(W2t + (size_t)r * HD + c8 * 8);
  }
  __syncthreads();

  const int strip = blockIdx.x * 4 + wv;
  const u16* Arow = A + (size_t)(strip * 16 + col) * HD;

  f32x4 acc[8];
#pragma unroll
  for (int t = 0; t < 8; ++t) acc[t] = (f32x4){0.f, 0.f, 0.f, 0.f};
#pragma unroll
  for (int kk = 0; kk < HD; kk += 32) {
    bf16x8 a = *(const bf16x8*)(Arow + kk + kg * 8);
#pragma unroll
    for (int t = 0; t < 8; ++t) {
      bf16x8 b = *(const bf16x8*)&W1[t * 16 + col][kk + kg * 8];
      acc[t] = __builtin_amdgcn_mfma_f32_16x16x32_bf16(a, b, acc[t], 0, 0, 0);
    }
  }
#pragma unroll
  for (int t = 0; t < 8; ++t) {
    int c = t * 16 + col;
    float bb = b1[c];
#pragma unroll
    for (int r = 0; r < 4; ++r) {
      float v = acc[t][r] + bb;
      v = v > 0.f ? v : expm1f(v);
      H[wv * 16 + kg * 4 + r][c] = f2bf(v);
    }
  }
  __syncthreads();

  f32x4 acc2[4];
#pragma unroll
  for (int t = 0; t < 4; ++t) acc2[t] = (f32x4){0.f, 0.f, 0.f, 0.f};
#pragma unroll
  for (int kk = 0; kk < HD; kk += 32) {
    bf16x8 a = *(const bf16x8*)&H[wv * 16 + col][kk + kg * 8];
#pragma unroll
    for (int t = 0; t < 4; ++t) {
      bf16x8 b = *(const bf16x8*)&W2[t * 16 + col][kk + kg * 8];
      acc2[t] = __builtin_amdgcn_mfma_f32_16x16x32_bf16(a, b, acc2[t], 0, 0, 0);
    }
  }
  __syncthreads();
#pragma unroll
  for (int t = 0; t < 4; ++t) {
    int c = t * 16 + col;
    float bb = b2[c];
#pragma unroll
    for (int r = 0; r < 4; ++r) {
      float* Hr = (float*)&H[wv * 16 + kg * 4 + r][0];
      Hr[c] = acc2[t][r] + bb;
    }
  }
  __syncthreads();
  {
    int r0 = lane >> 4, seg = lane & 15;
#pragma unroll
    for (int rr = 0; rr < 16; rr += 4) {
      int row = rr + r0;
      *(float4*)((char*)(out + (size_t)(strip * 16 + row) * 64) + seg * 16) =
          *(const float4*)((const char*)&H[wv * 16 + row][0] + seg * 16);
    }
  }
}

extern "C" void kernel_launch(void* const* d_in, const int* in_sizes, int n_in,
                              void* d_out, int out_size, void* d_ws, size_t ws_size,
                              hipStream_t stream) {
  const float* x = (const float*)d_in[0];
  const int* ei  = (const int*)d_in[1];
  const float* p[30];
  for (int i = 0; i < 30 && i < n_in; ++i) p[i] = (const float*)d_in[i];

  const size_t FEAT = (size_t)NODES * HD;
  u16* xb   = (u16*)d_ws;     // persistent 'cur' buffer
  u16* tmp  = xb + FEAT;      // gather target
  u16* wt   = tmp + FEAT;
  u16* wts[8];
  for (int m = 0; m < 8; ++m) wts[m] = wt + (size_t)m * HD * HD;
  int* off    = (int*)(wt + 8 * HD * HD);
  int* cursor = off + (NODES + 1);
  int* slot   = cursor + NODES;
  int* bsum   = slot + EDGES;

  dim3 blk(256);
  const int edgeGrid = (EDGES + 255) / 256;   // 2344
  const int gathGrid = NODES / 8;             // 5000
  const int gemmGrid = NODES / 64;            // 625
  const int scanGrid = 40;

  WPrep wp;
  const int widx[8] = {2, 8, 10, 16, 18, 24, 26, 28};
  for (int m = 0; m < 8; ++m) { wp.s[m] = p[widx[m]]; wp.d[m] = wts[m]; }
  prep_all<<<5285, blk, 0, stream>>>((const float4*)x, (ushort4*)xb, wp, cursor);

  hist_dst<<<edgeGrid, blk, 0, stream>>>(ei, cursor);
  scan1<<<scanGrid, 1024, 0, stream>>>(cursor, off, bsum);
  scan23<<<scanGrid, 1024, 0, stream>>>(off, cursor, bsum);
  fill_csr<<<edgeGrid, blk, 0, stream>>>(ei, cursor, slot);

  // 3 GIN layers: gather (xb -> tmp), fused MLP (tmp -> xb)
  for (int l = 0; l < 3; ++l) {
    const int base = 2 + l * 8;
    gather_agg<<<gathGrid, blk, 0, stream>>>(xb, off, slot, tmp);
    mlp_fused<<<gemmGrid, blk, 0, stream>>>(
        tmp, wts[l * 2], p[base + 1], p[base + 2], p[base + 3], p[base + 4],
        p[base + 5], wts[l * 2 + 1], p[base + 7], xb);
  }

  head_fused<<<gemmGrid, blk, 0, stream>>>(
      xb, wts[6], p[27], wts[7], p[29], (float*)d_out);
}